// Round 3
// baseline (87.902 us; speedup 1.0000x reference)
//
#include <hip/hip_runtime.h>
#include <hip/hip_bf16.h>
#include <math.h>

// Problem: image_feats (128,64,128) fp32 -> F0: 128 x 8192
//          lang_feats  (128,32,128) fp32 -> F1: 128 x 4096
//          out (128,) fp32 = column sums over i of exp(A_g)*(A_g - A_f)
//
// Gram via MFMA 32x32x16 bf16 with hi/lo fp32 splitting (4 products),
// fragments loaded directly from global (no LDS). Diagonal dist forced to 0
// (matches reference construction), so summation order is free.

#define NROW 128
#define PAIRS 16384
#define D0 8192
#define D1 4096
#define CK 64
#define NC0 128          // D0/CK
#define NC1 64           // D1/CK
#define NCHUNK 192

typedef short v8s  __attribute__((ext_vector_type(8)));
typedef float v16f __attribute__((ext_vector_type(16)));

union Frag {
    v8s s;
    __hip_bfloat162 h[4];
};

__device__ __forceinline__ void splitPair(float a, float b, Frag& hi, Frag& lo, int idx) {
    __hip_bfloat162 h = __float22bfloat162_rn(make_float2(a, b));
    const float ra = a - __bfloat162float(h.x);
    const float rb = b - __bfloat162float(h.y);
    __hip_bfloat162 l = __float22bfloat162_rn(make_float2(ra, rb));
    hi.h[idx] = h;
    lo.h[idx] = l;
}

__device__ __forceinline__ void loadFrag(const float* __restrict__ p, Frag& hi, Frag& lo) {
    const float4 v0 = *(const float4*)(p);
    const float4 v1 = *(const float4*)(p + 4);
    splitPair(v0.x, v0.y, hi, lo, 0);
    splitPair(v0.z, v0.w, hi, lo, 1);
    splitPair(v1.x, v1.y, hi, lo, 2);
    splitPair(v1.z, v1.w, hi, lo, 3);
}

// ---------------------------------------------------------------------------
// Kernel 1: one block per 64-column K-chunk; 4 waves as 2x2, each wave owns a
// 64x64 output region = 2x2 MFMA 32x32 tiles. A/B fragments: lane&31 = row,
// (lane>>5)*8 = k-offset, 8 consecutive fp32 -> bf16 hi/lo.
// ---------------------------------------------------------------------------
__global__ __launch_bounds__(256) void k_gram(
    const float* __restrict__ F0, const float* __restrict__ F1,
    float* __restrict__ partials, float* __restrict__ diagP,
    float* __restrict__ out)
{
    const int b = blockIdx.x;
    const int t = threadIdx.x;
    if (b == 0 && t < NROW) out[t] = 0.0f;   // zero for k_kl atomics

    const float* F; int D, k0;
    if (b < NC0) { F = F0; D = D0; k0 = b * CK; }
    else         { F = F1; D = D1; k0 = (b - NC0) * CK; }

    const int wave  = t >> 6;
    const int wy    = wave >> 1;
    const int wx    = wave & 1;
    const int lane  = t & 63;
    const int r32   = lane & 31;
    const int khalf = lane >> 5;

    const int rA0 = wy * 64 + r32;
    const int rA1 = wy * 64 + 32 + r32;
    const int rB0 = wx * 64 + r32;
    const int rB1 = wx * 64 + 32 + r32;

    v16f acc[2][2];
#pragma unroll
    for (int ti = 0; ti < 2; ++ti)
#pragma unroll
        for (int tj = 0; tj < 2; ++tj)
#pragma unroll
            for (int r = 0; r < 16; ++r) acc[ti][tj][r] = 0.0f;

#pragma unroll
    for (int g = 0; g < CK / 16; ++g) {
        const int col = k0 + g * 16 + khalf * 8;
        Frag Ah[2], Al[2], Bh[2], Bl[2];
        loadFrag(F + (size_t)rA0 * D + col, Ah[0], Al[0]);
        loadFrag(F + (size_t)rA1 * D + col, Ah[1], Al[1]);
        loadFrag(F + (size_t)rB0 * D + col, Bh[0], Bl[0]);
        loadFrag(F + (size_t)rB1 * D + col, Bh[1], Bl[1]);
#pragma unroll
        for (int ti = 0; ti < 2; ++ti)
#pragma unroll
            for (int tj = 0; tj < 2; ++tj) {
                acc[ti][tj] = __builtin_amdgcn_mfma_f32_32x32x16_bf16(
                    Ah[ti].s, Bh[tj].s, acc[ti][tj], 0, 0, 0);
                acc[ti][tj] = __builtin_amdgcn_mfma_f32_32x32x16_bf16(
                    Ah[ti].s, Bl[tj].s, acc[ti][tj], 0, 0, 0);
                acc[ti][tj] = __builtin_amdgcn_mfma_f32_32x32x16_bf16(
                    Al[ti].s, Bh[tj].s, acc[ti][tj], 0, 0, 0);
                acc[ti][tj] = __builtin_amdgcn_mfma_f32_32x32x16_bf16(
                    Al[ti].s, Bl[tj].s, acc[ti][tj], 0, 0, 0);
            }
    }

    // C/D layout (verified m74/m101): col = lane&31, row = (reg&3)+8*(reg>>2)+4*(lane>>5)
    float* __restrict__ pout = partials + (size_t)b * PAIRS;
#pragma unroll
    for (int ti = 0; ti < 2; ++ti)
#pragma unroll
        for (int tj = 0; tj < 2; ++tj) {
            const int rowbase = wy * 64 + ti * 32;
            const int n = wx * 64 + tj * 32 + r32;
#pragma unroll
            for (int r = 0; r < 16; ++r) {
                const int m = rowbase + (r & 3) + 8 * (r >> 2) + 4 * khalf;
                const float v = acc[ti][tj][r];
                pout[m * NROW + n] = v;
                if (m == n) diagP[b * NROW + m] = v;   // coalesced-reducible diag copy
            }
        }
}

// ---------------------------------------------------------------------------
// Kernel 2: block = row i, 256 threads. Lower half (s=0) handles set f,
// upper half (s=1) handles set g, concurrently: split-K reduce (4-acc unroll),
// diagonal reduce (coalesced), log-softmax per half, join, KL, atomic col-sum.
// ---------------------------------------------------------------------------
__device__ __forceinline__ float waveMax64(float v) {
#pragma unroll
    for (int off = 32; off > 0; off >>= 1) v = fmaxf(v, __shfl_xor(v, off, 64));
    return v;
}
__device__ __forceinline__ float waveSum64(float v) {
#pragma unroll
    for (int off = 32; off > 0; off >>= 1) v += __shfl_xor(v, off, 64);
    return v;
}

__global__ __launch_bounds__(256) void k_kl(
    const float* __restrict__ partials, const float* __restrict__ diagP,
    const float* __restrict__ temp, float* __restrict__ out)
{
    __shared__ float red[4];
    __shared__ float gii_s[2];
    __shared__ float Arow[2][NROW];

    const int i = blockIdx.x;
    const int t = threadIdx.x;
    const int s = t >> 7;          // 0 = image set, 1 = lang set
    const int j = t & 127;
    const int w = t >> 6;          // wave id 0..3
    const float et = expf(temp[0]);

    const int   base = s ? NC0 : 0;
    const int   nc   = s ? NC1 : NC0;
    const float* Ps  = partials + (size_t)base * PAIRS;
    const float* Ds  = diagP + base * NROW;

    // gij = sum over chunks of P[c][i][j]  (coalesced in j)
    float a0 = 0.f, a1 = 0.f, a2 = 0.f, a3 = 0.f;
    {
        const float* p = Ps + i * NROW + j;
        for (int c = 0; c < nc; c += 4) {
            a0 += p[(size_t)(c + 0) * PAIRS];
            a1 += p[(size_t)(c + 1) * PAIRS];
            a2 += p[(size_t)(c + 2) * PAIRS];
            a3 += p[(size_t)(c + 3) * PAIRS];
        }
    }
    const float gij = (a0 + a1) + (a2 + a3);

    // gjj = sum over chunks of diag[c][j]  (coalesced in j)
    float d0 = 0.f, d1 = 0.f, d2 = 0.f, d3 = 0.f;
    {
        const float* p = Ds + j;
        for (int c = 0; c < nc; c += 4) {
            d0 += p[(c + 0) * NROW];
            d1 += p[(c + 1) * NROW];
            d2 += p[(c + 2) * NROW];
            d3 += p[(c + 3) * NROW];
        }
    }
    const float gjj = (d0 + d1) + (d2 + d3);

    if (j == i) gii_s[s] = gjj;
    __syncthreads();
    const float gii = gii_s[s];

    // diagonal is exactly zero by construction in the reference
    const float sq   = (i == j) ? 0.0f : (gii + gjj - 2.0f * gij);
    const float dist = sq > 0.0f ? sqrtf(sq) : 0.0f;
    const float pre  = -dist * et;

    // per-half (128-thread) max
    float m = waveMax64(pre);
    if ((t & 63) == 0) red[w] = m;
    __syncthreads();
    m = fmaxf(red[2 * s], red[2 * s + 1]);
    __syncthreads();

    // per-half sum of exp
    float e = expf(pre - m);
    float sum = waveSum64(e);
    if ((t & 63) == 0) red[w] = sum;
    __syncthreads();
    sum = red[2 * s] + red[2 * s + 1];

    const float A = pre - (m + logf(sum));
    Arow[s][j] = A;
    __syncthreads();

    if (s == 0) {
        const float Af = Arow[0][j];
        const float Ag = Arow[1][j];
        atomicAdd(out + j, expf(Ag) * (Ag - Af));   // column sum over i
    }
}

// ---------------------------------------------------------------------------
extern "C" void kernel_launch(void* const* d_in, const int* in_sizes, int n_in,
                              void* d_out, int out_size, void* d_ws, size_t ws_size,
                              hipStream_t stream)
{
    const float* img  = (const float*)d_in[0];
    const float* lng  = (const float*)d_in[1];
    const float* temp = (const float*)d_in[2];
    float* out = (float*)d_out;

    float* partials = (float*)d_ws;                       // 192*16384*4 = 12.6 MB
    float* diagP    = partials + (size_t)NCHUNK * PAIRS;  // 192*128*4   = 98 KB

    k_gram<<<NCHUNK, 256, 0, stream>>>(img, lng, partials, diagP, out);
    k_kl<<<NROW, 256, 0, stream>>>(partials, diagP, temp, out);
}